// Round 1
// baseline (1783.640 us; speedup 1.0000x reference)
//
#include <hip/hip_runtime.h>

// ---------------------------------------------------------------------------
// GraphNetwork: edge MLP (gather + [E,384]@[384,256] relu @[256,128]) with
// fused segment-sum via atomics, then node MLP ([N,384]@...). bf16 MFMA.
// ---------------------------------------------------------------------------

typedef unsigned short ushort_t;
typedef __attribute__((ext_vector_type(8))) short bf16x8;
typedef __attribute__((ext_vector_type(4))) float f32x4;

#define MFMA16(a, b, c) __builtin_amdgcn_mfma_f32_16x16x32_bf16(a, b, c, 0, 0, 0)

__device__ __forceinline__ ushort_t f2bf(float f) {
    unsigned int u = __builtin_bit_cast(unsigned int, f);
    u += 0x7fffu + ((u >> 16) & 1u);   // RNE
    return (ushort_t)(u >> 16);
}

// Pack fp32 row-major W[K][N] -> bf16 Wp[((k>>3)*N + n)*8 + (k&7)]
// so a B-fragment (8 consecutive k for fixed n) is one contiguous 16B unit.
__global__ void pack_all(const float* __restrict__ eW1, const float* __restrict__ eW2,
                         const float* __restrict__ nW1, const float* __restrict__ nW2,
                         ushort_t* __restrict__ eW1p, ushort_t* __restrict__ eW2p,
                         ushort_t* __restrict__ nW1p, ushort_t* __restrict__ nW2p) {
    int idx = blockIdx.x * 256 + threadIdx.x;   // total 262144
    const float* W; ushort_t* Wp; int N, local;
    if (idx < 98304)       { W = eW1; Wp = eW1p; N = 256; local = idx; }
    else if (idx < 131072) { W = eW2; Wp = eW2p; N = 128; local = idx - 98304; }
    else if (idx < 229376) { W = nW1; Wp = nW1p; N = 256; local = idx - 131072; }
    else                   { W = nW2; Wp = nW2p; N = 128; local = idx - 229376; }
    int k = local / N;
    int n = local - k * N;
    Wp[((size_t)((k >> 3) * N + n)) * 8 + (k & 7)] = f2bf(W[(size_t)k * N + n]);
}

// A-tile: 64 rows x 384 k, bf16, pitch 392 (pad +8 -> 2-way bank pattern, free)
#define APITCH 392
// H-tile: 64 rows x 64 cols (strip), pitch 72
#define HPITCH 72

// ---------------------------------------------------------------------------
// Edge kernel: 64 edges / block, 256 threads (4 waves, each 16 rows).
// ---------------------------------------------------------------------------
__global__ __launch_bounds__(256, 2)
void edge_kernel(const float* __restrict__ node_feat, const float* __restrict__ edge_feat,
                 const int* __restrict__ senders, const int* __restrict__ receivers,
                 const ushort_t* __restrict__ W1p, const float* __restrict__ b1,
                 const ushort_t* __restrict__ W2p, const float* __restrict__ b2,
                 float* __restrict__ new_edges, float* __restrict__ sent_agg,
                 float* __restrict__ recv_agg) {
    __shared__ ushort_t Alds[64 * APITCH];  // 50176 B
    __shared__ ushort_t Wlds[8192];         // 16384 B
    __shared__ ushort_t Hlds[64 * HPITCH];  //  9216 B

    const int tid = threadIdx.x;
    const int ebase = blockIdx.x * 64;

    // ---- gather + f32->bf16 convert: rows = [edge_feat | nf[send] | nf[recv]]
    for (int t = tid; t < 6144; t += 256) {       // 64 rows * 96 float4-pieces
        int row = t / 96;
        int p   = t - row * 96;
        int e   = ebase + row;
        int k0  = p * 4;
        const float* src;
        if (p < 32)      src = edge_feat + (size_t)e * 128 + k0;
        else if (p < 64) src = node_feat + (size_t)senders[e] * 128 + (k0 - 128);
        else             src = node_feat + (size_t)receivers[e] * 128 + (k0 - 256);
        float4 v = *(const float4*)src;
        ushort4 w;
        w.x = f2bf(v.x); w.y = f2bf(v.y); w.z = f2bf(v.z); w.w = f2bf(v.w);
        *(ushort4*)&Alds[row * APITCH + k0] = w;
    }
    __syncthreads();

    const int wv   = tid >> 6;       // wave 0..3 -> rows [wv*16, wv*16+16)
    const int lane = tid & 63;
    const int lrow = lane & 15;
    const int lq   = lane >> 4;
    const int arow = wv * 16 + lrow;

    f32x4 acc2[8];
#pragma unroll
    for (int i = 0; i < 8; i++) acc2[i] = (f32x4){0.f, 0.f, 0.f, 0.f};

#pragma unroll
    for (int s = 0; s < 4; s++) {                 // 4 strips of 64 H-cols
        const int sbase = s * 64;
        f32x4 acc1[4];
#pragma unroll
        for (int i = 0; i < 4; i++) acc1[i] = (f32x4){0.f, 0.f, 0.f, 0.f};

#pragma unroll
        for (int kc = 0; kc < 3; kc++) {          // K chunks of 128
            const int kcb = kc * 128;
            // stage W1 chunk [128k x 64n]: 1024 x 16B units
            for (int u = tid; u < 1024; u += 256) {
                int kq16 = u >> 6;
                int n    = u & 63;
                *(uint4*)&Wlds[u * 8] =
                    *(const uint4*)&W1p[(size_t)(((kcb >> 3) + kq16) * 256 + sbase + n) * 8];
            }
            __syncthreads();
#pragma unroll
            for (int kt = 0; kt < 4; kt++) {
                bf16x8 a = *(const bf16x8*)&Alds[arow * APITCH + kcb + kt * 32 + lq * 8];
#pragma unroll
                for (int nt = 0; nt < 4; nt++) {
                    bf16x8 b = *(const bf16x8*)&Wlds[((kt * 4 + lq) * 64 + nt * 16 + lrow) * 8];
                    acc1[nt] = MFMA16(a, b, acc1[nt]);
                }
            }
            __syncthreads();
        }

        // bias + relu -> bf16 H strip (C layout: col=lane&15, row=lq*4+reg)
#pragma unroll
        for (int nt = 0; nt < 4; nt++) {
            float bb = b1[sbase + nt * 16 + lrow];
#pragma unroll
            for (int rg = 0; rg < 4; rg++) {
                int row = wv * 16 + lq * 4 + rg;
                float v = acc1[nt][rg] + bb;
                v = v > 0.f ? v : 0.f;
                Hlds[row * HPITCH + nt * 16 + lrow] = f2bf(v);
            }
        }
        __syncthreads();

        // stage W2 chunk [64k x 128n]: 1024 x 16B units
        for (int u = tid; u < 1024; u += 256) {
            int kq16 = u >> 7;
            int n    = u & 127;
            *(uint4*)&Wlds[u * 8] = *(const uint4*)&W2p[(size_t)((s * 8 + kq16) * 128 + n) * 8];
        }
        __syncthreads();

        // GEMM2 partial: k in [s*64, s*64+64)
#pragma unroll
        for (int kt = 0; kt < 2; kt++) {
            bf16x8 a = *(const bf16x8*)&Hlds[arow * HPITCH + kt * 32 + lq * 8];
#pragma unroll
            for (int nt = 0; nt < 8; nt++) {
                bf16x8 b = *(const bf16x8*)&Wlds[((kt * 4 + lq) * 128 + nt * 16 + lrow) * 8];
                acc2[nt] = MFMA16(a, b, acc2[nt]);
            }
        }
        __syncthreads();   // Wlds/Hlds reused next strip
    }

    // ---- epilogue: +b2, write new_edges, atomic segment sums
    float bv[8];
#pragma unroll
    for (int nt = 0; nt < 8; nt++) bv[nt] = b2[nt * 16 + lrow];
#pragma unroll
    for (int rg = 0; rg < 4; rg++) {
        int row = wv * 16 + lq * 4 + rg;
        int e   = ebase + row;
        int si  = senders[e];
        int ri  = receivers[e];
        float* er = new_edges + (size_t)e * 128;
        float* sa = sent_agg + (size_t)si * 128;
        float* ra = recv_agg + (size_t)ri * 128;
#pragma unroll
        for (int nt = 0; nt < 8; nt++) {
            int col = nt * 16 + lrow;
            float v = acc2[nt][rg] + bv[nt];
            er[col] = v;
            atomicAdd(sa + col, v);
            atomicAdd(ra + col, v);
        }
    }
}

// ---------------------------------------------------------------------------
// Node kernel: same structure, rows = [node_feat | sent_agg | recv_agg], tail-guarded.
// ---------------------------------------------------------------------------
__global__ __launch_bounds__(256, 2)
void node_kernel(const float* __restrict__ node_feat, const float* __restrict__ sent_agg,
                 const float* __restrict__ recv_agg,
                 const ushort_t* __restrict__ W1p, const float* __restrict__ b1,
                 const ushort_t* __restrict__ W2p, const float* __restrict__ b2,
                 float* __restrict__ new_nodes) {
    __shared__ ushort_t Alds[64 * APITCH];
    __shared__ ushort_t Wlds[8192];
    __shared__ ushort_t Hlds[64 * HPITCH];

    const int tid = threadIdx.x;
    const int nbase = blockIdx.x * 64;

    for (int t = tid; t < 6144; t += 256) {
        int row = t / 96;
        int p   = t - row * 96;
        int n   = nbase + row;
        int k0  = p * 4;
        float4 v = (float4){0.f, 0.f, 0.f, 0.f};
        if (n < 50000) {
            const float* src;
            if (p < 32)      src = node_feat + (size_t)n * 128 + k0;
            else if (p < 64) src = sent_agg + (size_t)n * 128 + (k0 - 128);
            else             src = recv_agg + (size_t)n * 128 + (k0 - 256);
            v = *(const float4*)src;
        }
        ushort4 w;
        w.x = f2bf(v.x); w.y = f2bf(v.y); w.z = f2bf(v.z); w.w = f2bf(v.w);
        *(ushort4*)&Alds[row * APITCH + k0] = w;
    }
    __syncthreads();

    const int wv   = tid >> 6;
    const int lane = tid & 63;
    const int lrow = lane & 15;
    const int lq   = lane >> 4;
    const int arow = wv * 16 + lrow;

    f32x4 acc2[8];
#pragma unroll
    for (int i = 0; i < 8; i++) acc2[i] = (f32x4){0.f, 0.f, 0.f, 0.f};

#pragma unroll
    for (int s = 0; s < 4; s++) {
        const int sbase = s * 64;
        f32x4 acc1[4];
#pragma unroll
        for (int i = 0; i < 4; i++) acc1[i] = (f32x4){0.f, 0.f, 0.f, 0.f};

#pragma unroll
        for (int kc = 0; kc < 3; kc++) {
            const int kcb = kc * 128;
            for (int u = tid; u < 1024; u += 256) {
                int kq16 = u >> 6;
                int n    = u & 63;
                *(uint4*)&Wlds[u * 8] =
                    *(const uint4*)&W1p[(size_t)(((kcb >> 3) + kq16) * 256 + sbase + n) * 8];
            }
            __syncthreads();
#pragma unroll
            for (int kt = 0; kt < 4; kt++) {
                bf16x8 a = *(const bf16x8*)&Alds[arow * APITCH + kcb + kt * 32 + lq * 8];
#pragma unroll
                for (int nt = 0; nt < 4; nt++) {
                    bf16x8 b = *(const bf16x8*)&Wlds[((kt * 4 + lq) * 64 + nt * 16 + lrow) * 8];
                    acc1[nt] = MFMA16(a, b, acc1[nt]);
                }
            }
            __syncthreads();
        }

#pragma unroll
        for (int nt = 0; nt < 4; nt++) {
            float bb = b1[sbase + nt * 16 + lrow];
#pragma unroll
            for (int rg = 0; rg < 4; rg++) {
                int row = wv * 16 + lq * 4 + rg;
                float v = acc1[nt][rg] + bb;
                v = v > 0.f ? v : 0.f;
                Hlds[row * HPITCH + nt * 16 + lrow] = f2bf(v);
            }
        }
        __syncthreads();

        for (int u = tid; u < 1024; u += 256) {
            int kq16 = u >> 7;
            int n    = u & 127;
            *(uint4*)&Wlds[u * 8] = *(const uint4*)&W2p[(size_t)((s * 8 + kq16) * 128 + n) * 8];
        }
        __syncthreads();

#pragma unroll
        for (int kt = 0; kt < 2; kt++) {
            bf16x8 a = *(const bf16x8*)&Hlds[arow * HPITCH + kt * 32 + lq * 8];
#pragma unroll
            for (int nt = 0; nt < 8; nt++) {
                bf16x8 b = *(const bf16x8*)&Wlds[((kt * 4 + lq) * 128 + nt * 16 + lrow) * 8];
                acc2[nt] = MFMA16(a, b, acc2[nt]);
            }
        }
        __syncthreads();
    }

    float bv[8];
#pragma unroll
    for (int nt = 0; nt < 8; nt++) bv[nt] = b2[nt * 16 + lrow];
#pragma unroll
    for (int rg = 0; rg < 4; rg++) {
        int row = wv * 16 + lq * 4 + rg;
        int n   = nbase + row;
        if (n < 50000) {
            float* out = new_nodes + (size_t)n * 128;
#pragma unroll
            for (int nt = 0; nt < 8; nt++) {
                int col = nt * 16 + lrow;
                out[col] = acc2[nt][rg] + bv[nt];
            }
        }
    }
}

// ---------------------------------------------------------------------------
extern "C" void kernel_launch(void* const* d_in, const int* in_sizes, int n_in,
                              void* d_out, int out_size, void* d_ws, size_t ws_size,
                              hipStream_t stream) {
    const float* node_feat = (const float*)d_in[0];
    const float* edge_feat = (const float*)d_in[1];
    const int*   senders   = (const int*)d_in[2];
    const int*   receivers = (const int*)d_in[3];
    const float* eW1 = (const float*)d_in[4];
    const float* eb1 = (const float*)d_in[5];
    const float* eW2 = (const float*)d_in[6];
    const float* eb2 = (const float*)d_in[7];
    const float* nW1 = (const float*)d_in[8];
    const float* nb1 = (const float*)d_in[9];
    const float* nW2 = (const float*)d_in[10];
    const float* nb2 = (const float*)d_in[11];

    float* new_nodes = (float*)d_out;                 // 50000*128
    float* new_edges = (float*)d_out + 6400000;       // 600000*128

    // ws layout: sent_agg f32[6.4M] | recv_agg f32[6.4M] | packed bf16 weights
    float* sent_agg = (float*)d_ws;
    float* recv_agg = sent_agg + 6400000;
    ushort_t* eW1p = (ushort_t*)((char*)d_ws + 51200000);
    ushort_t* eW2p = eW1p + 98304;
    ushort_t* nW1p = eW2p + 32768;
    ushort_t* nW2p = nW1p + 98304;

    hipMemsetAsync(d_ws, 0, 51200000, stream);
    pack_all<<<1024, 256, 0, stream>>>(eW1, eW2, nW1, nW2, eW1p, eW2p, nW1p, nW2p);
    edge_kernel<<<9375, 256, 0, stream>>>(node_feat, edge_feat, senders, receivers,
                                          eW1p, eb1, eW2p, eb2,
                                          new_edges, sent_agg, recv_agg);
    node_kernel<<<782, 256, 0, stream>>>(node_feat, sent_agg, recv_agg,
                                         nW1p, nb1, nW2p, nb2, new_nodes);
}